// Round 13
// baseline (181.151 us; speedup 1.0000x reference)
//
#include <hip/hip_runtime.h>
#include <hip/hip_bf16.h>

// Problem geometry
#define N_ROWS 32000   // Q_OUT*Q_IN*NUM_P
#define SB     12      // SCALAR_BASIS
#define FC     720     // FILTER_C
#define FD     2704    // FILTER_DIM
#define OCOLS  2704    // DIM_OUT*DIM_IN
#define OPAD   2816    // OCOLS padded
#define ANGD   25
#define PDIM   300     // SB * ANGD
#define KST    320     // PDIM padded (5 subtiles of 64)
#define NCIT   43      // col-iters of 64 (43*64 = 2752 >= 2704)

typedef __attribute__((ext_vector_type(8))) short bf16x8;
typedef __attribute__((ext_vector_type(4))) float f32x4;

__device__ __forceinline__ void gload16(const void* g, void* l) {
    __builtin_amdgcn_global_load_lds(
        (const __attribute__((address_space(1))) void*)g,
        (__attribute__((address_space(3))) void*)l, 16, 0, 0);
}

// ---------------------------------------------------------------------------
// Kernel A (round-9 proven): V[o, s*25+a] = sum_c TP[o,...]*(W[s,...]/sqrt12)
// ---------------------------------------------------------------------------
__global__ __launch_bounds__(320) void build_V(
    const float* __restrict__ TP,
    const float* __restrict__ W,
    __hip_bfloat16* __restrict__ V)
{
    const int o   = blockIdx.x;   // 0..OPAD-1
    const int tid = threadIdx.x;  // 0..319
    __shared__ float s_tp[FD];        // 10816 B
    __shared__ float s_w[SB * FC];    // 34560 B

    const float inv = 0.28867513459481288f; // 1/sqrt(12)
    for (int i = tid; i < SB * FC; i += 320) s_w[i] = W[i] * inv;
    if (o < OCOLS) {
        for (int i = tid; i < FD; i += 320) s_tp[i] = TP[(size_t)o * FD + i];
    } else {
        for (int i = tid; i < FD; i += 320) s_tp[i] = 0.f;
    }
    __syncthreads();

    const int p = tid;   // one p per thread
    float acc = 0.f;
    if (p < PDIM) {
        const int s     = p / ANGD;
        const int alpha = p - s * ANGD;
        int m, off, sco, al, Cl;
        if (alpha < 1)       { m = 1; off = 0;    sco = 0;   al = 0;  Cl = 144; }
        else if (alpha < 4)  { m = 3; off = 144;  sco = 144; al = 1;  Cl = 272; }
        else if (alpha < 9)  { m = 5; off = 960;  sco = 416; al = 4;  Cl = 208; }
        else if (alpha < 16) { m = 7; off = 2000; sco = 624; al = 9;  Cl = 80;  }
        else                 { m = 9; off = 2560; sco = 704; al = 16; Cl = 16;  }
        const int j = alpha - al;
        const float* tp = s_tp + off + j;
        const float* ww = s_w + s * FC + sco;
        float a0 = 0.f, a1 = 0.f, a2 = 0.f, a3 = 0.f;
        for (int c = 0; c < Cl; c += 4) {
            a0 += tp[(c + 0) * m] * ww[c + 0];
            a1 += tp[(c + 1) * m] * ww[c + 1];
            a2 += tp[(c + 2) * m] * ww[c + 2];
            a3 += tp[(c + 3) * m] * ww[c + 3];
        }
        acc = (a0 + a1) + (a2 + a3);
    }
    if (p < KST) V[(size_t)o * KST + p] = __float2bfloat16(acc);
}

// ---------------------------------------------------------------------------
// Kernel B (round-9 proven): X[n, s*25+a] = sk[n,s] * ang[n,a], bf16.
// ---------------------------------------------------------------------------
__global__ void build_X(const float* __restrict__ sk,
                        const float* __restrict__ ang,
                        __hip_bfloat16* __restrict__ X)
{
    const int idx = blockIdx.x * 256 + threadIdx.x;
    if (idx >= N_ROWS * (KST / 8)) return;
    const int n  = idx / (KST / 8);
    const int p0 = (idx - n * (KST / 8)) * 8;
    const float* skn  = sk  + (size_t)n * SB;
    const float* angn = ang + (size_t)n * ANGD;
    alignas(16) __hip_bfloat16 tmp[8];
    #pragma unroll
    for (int u = 0; u < 8; ++u) {
        const int p = p0 + u;
        float v = 0.f;
        if (p < PDIM) {
            const int s = p / ANGD;
            const int a = p - s * ANGD;
            v = skn[s] * angn[a];
        }
        tmp[u] = __float2bfloat16(v);
    }
    *(bf16x8*)(X + (size_t)n * KST + p0) = *(const bf16x8*)tmp;
}

// ---------------------------------------------------------------------------
// Kernel C: ROW-PERSISTENT GEMM. One block per 128-row stripe (grid 250).
// Phase 1: stage A[128][320] to LDS (verified swizzled STAGE), read each
// wave's af[4][10] to REGISTERS (X read from HBM exactly once).
// Phase 2: LDS recycled as B double-buffer (2 x 40 KB); loop 43 col-tiles
// of 64: stage B(t+1), swizzled ds_read B-frags, 40 MFMA (swapped -> D^T),
// NORMAL f32x4 stores (X no longer in L2 -> pollution harmless; stores can
// run at the ~6.8 TB/s fill-kernel rate).
// vmcnt ledger: per iter stage(5) then stores(4) -> vmcnt(4) drains stage
// and prior stores. Full iters (t<=41) store unguarded (max o=2687<2704) so
// counts are wave-uniform; last iter is partial and has no successor.
// ---------------------------------------------------------------------------
__global__ __launch_bounds__(512, 2) void gemm_bt(
    const __hip_bfloat16* __restrict__ A,   // X: (N_ROWS, KST)
    const __hip_bfloat16* __restrict__ Bv,  // V: (OPAD, KST)
    float* __restrict__ C)
{
    __shared__ __align__(1024) char lds[81920];
    // phase 1: A subtiles kt at lds + kt*16384 (80 KB)
    // phase 2: B halves at lds + half*40960, subtile kk at +kk*8192

    const int tid  = threadIdx.x;
    const int wave = tid >> 6;         // 0..7
    const int lane = tid & 63;
    const int bm   = blockIdx.x;       // 250 row stripes
    const size_t arow0 = (size_t)bm * 128;

    const int wr = wave >> 2;          // 0..1 (64-row half)
    const int wc = wave & 3;           // 0..3 (16-col slab)

    // staging constants (LDS linear dest; global source pre-swizzled)
    const int lrow  = lane >> 3;
    const int lslot = ((lane & 7) ^ (lrow & 7)) << 4;
    // reader constants (slot = (ks*4+koct) ^ (row&7); row&7 == lane&7 here)
    const int rl   = lane & 15;
    const int koct = lane >> 4;
    const int sK0 = ((0 * 4 + koct) ^ (lane & 7)) << 4;
    const int sK1 = ((1 * 4 + koct) ^ (lane & 7)) << 4;

    // ---- phase 1: stage A (5 subtiles of [128][64]) and load to regs ----
    #pragma unroll
    for (int kt = 0; kt < 5; ++kt) {
        const char* g0 = (const char*)A
            + (arow0 + (size_t)(wave * 8 + lrow)) * (KST * 2)
            + (size_t)kt * 128 + lslot;
        gload16(g0,                          lds + kt * 16384 + wave * 1024);
        gload16(g0 + (size_t)64 * (KST * 2), lds + kt * 16384 + 8192 + wave * 1024);
    }
    asm volatile("s_waitcnt vmcnt(0)" ::: "memory");
    __builtin_amdgcn_s_barrier();

    bf16x8 af[4][10];   // wave's 64 rows x K=320 (160 VGPR)
    #pragma unroll
    for (int kt = 0; kt < 5; ++kt)
        #pragma unroll
        for (int m = 0; m < 4; ++m) {
            const int r = wr * 64 + m * 16 + rl;
            af[m][2 * kt]     = *(const bf16x8*)(lds + kt * 16384 + r * 128 + sK0);
            af[m][2 * kt + 1] = *(const bf16x8*)(lds + kt * 16384 + r * 128 + sK1);
        }
    asm volatile("s_waitcnt lgkmcnt(0)" ::: "memory");
    __builtin_amdgcn_sched_barrier(0);
    __builtin_amdgcn_s_barrier();      // all waves done reading A; LDS free

    // ---- phase 2: col-tile loop with B double-buffer ----
    auto STAGE_B = [&](int ct, int half) {
        const char* g0 = (const char*)Bv
            + ((size_t)ct * 64 + (size_t)(wave * 8 + lrow)) * (KST * 2) + lslot;
        #pragma unroll
        for (int kk = 0; kk < 5; ++kk)
            gload16(g0 + (size_t)kk * 128,
                    lds + half * 40960 + kk * 8192 + wave * 1024);
    };

    STAGE_B(0, 0);
    asm volatile("s_waitcnt vmcnt(0)" ::: "memory");
    __builtin_amdgcn_s_barrier();

    const int brl = wc * 16 + rl;      // B row within 64-row tile

    for (int t = 0; t < NCIT; ++t) {
        const int half = t & 1;
        if (t + 1 < NCIT) STAGE_B(t + 1, half ^ 1);

        f32x4 acc[4] = {};
        char* const bh = lds + half * 40960;
        #pragma unroll
        for (int kk = 0; kk < 5; ++kk) {
            const bf16x8 b0 = *(const bf16x8*)(bh + kk * 8192 + brl * 128 + sK0);
            const bf16x8 b1 = *(const bf16x8*)(bh + kk * 8192 + brl * 128 + sK1);
            #pragma unroll
            for (int m = 0; m < 4; ++m)
                acc[m] = __builtin_amdgcn_mfma_f32_16x16x32_bf16(
                    b0, af[m][2 * kk], acc[m], 0, 0, 0);
            #pragma unroll
            for (int m = 0; m < 4; ++m)
                acc[m] = __builtin_amdgcn_mfma_f32_16x16x32_bf16(
                    b1, af[m][2 * kk + 1], acc[m], 0, 0, 0);
        }

        // D^T frag: lane stores 4 consecutive o at M = arow0+wr*64+m*16+rl
        const int o = t * 64 + wc * 16 + koct * 4;
        if (t < NCIT - 1) {
            // full iter: o <= 41*64+63 = 2687 < OCOLS, store unguarded
            #pragma unroll
            for (int m = 0; m < 4; ++m)
                *(f32x4*)(C + (size_t)(arow0 + wr * 64 + m * 16 + rl) * OCOLS + o)
                    = acc[m];
            asm volatile("s_waitcnt vmcnt(4)" ::: "memory");
            __builtin_amdgcn_s_barrier();
        } else {
            if (o < OCOLS) {   // wave-uniform: wc=0 fully in, wc>=1 fully out
                #pragma unroll
                for (int m = 0; m < 4; ++m)
                    *(f32x4*)(C + (size_t)(arow0 + wr * 64 + m * 16 + rl) * OCOLS + o)
                        = acc[m];
            }
        }
    }
}

// ---------------------------------------------------------------------------
extern "C" void kernel_launch(void* const* d_in, const int* in_sizes, int n_in,
                              void* d_out, int out_size, void* d_ws, size_t ws_size,
                              hipStream_t stream)
{
    const float* sk  = (const float*)d_in[0];   // (16,16,125,12)
    const float* ang = (const float*)d_in[1];   // (32000,25)
    const float* W   = (const float*)d_in[2];   // (12,720)
    const float* TP  = (const float*)d_in[3];   // (2704,2704)
    float* out = (float*)d_out;                 // (32000,2704)

    __hip_bfloat16* X  = (__hip_bfloat16*)d_ws;             // N_ROWS*KST bf16 (20.5 MB)
    __hip_bfloat16* Vb = X + (size_t)N_ROWS * KST;          // OPAD*KST bf16 (1.8 MB)

    build_V<<<OPAD, 320, 0, stream>>>(TP, W, Vb);
    build_X<<<(N_ROWS * (KST / 8) + 255) / 256, 256, 0, stream>>>(sk, ang, X);

    gemm_bt<<<N_ROWS / 128, 512, 0, stream>>>(X, Vb, out);
}

// Round 14
// 141.493 us; speedup vs baseline: 1.2803x; 1.2803x over previous
//
#include <hip/hip_runtime.h>
#include <hip/hip_bf16.h>

// Problem geometry
#define N_ROWS 32000   // Q_OUT*Q_IN*NUM_P
#define SB     12      // SCALAR_BASIS
#define FC     720     // FILTER_C
#define FD     2704    // FILTER_DIM
#define OCOLS  2704    // DIM_OUT*DIM_IN
#define OPAD   2816    // padded o (22*128)
#define ANGD   25
#define PDIM   300     // SB * ANGD
#define KST    320     // PDIM padded to 5*64 (main GEMM K)
#define NT     5       // main GEMM K tiles of 64
#define KP     2720    // FD padded to 85*32 (V-GEMM K)
#define NTV    85      // V-GEMM K tiles of 32
#define GPR    (KP/8)  // 340 groups per TPb row

typedef __attribute__((ext_vector_type(8))) short bf16x8;
typedef __attribute__((ext_vector_type(4))) float f32x4;

__device__ __forceinline__ void gload16(const void* g, void* l) {
    __builtin_amdgcn_global_load_lds(
        (const __attribute__((address_space(1))) void*)g,
        (__attribute__((address_space(3))) void*)l, 16, 0, 0);
}

__device__ __forceinline__ void decode_f(int f, int& c, int& j, int& a) {
    if (f < 144)       { c = f;                         j = 0;            a = 0;  }
    else if (f < 960)  { int t = f - 144;  c = 144 + t/3; j = t - (t/3)*3; a = 1;  }
    else if (f < 2000) { int t = f - 960;  c = 416 + t/5; j = t - (t/5)*5; a = 4;  }
    else if (f < 2560) { int t = f - 2000; c = 624 + t/7; j = t - (t/7)*7; a = 9;  }
    else               { int t = f - 2560; c = 704 + t/9; j = t - (t/9)*9; a = 16; }
}

// ---------------------------------------------------------------------------
// Kernel 1 (round-3 verified pattern): TP (2704x2704 f32) -> TPb bf16
// padded (OPAD x KP). float4 x2 loads, bf16x8 store.
// ---------------------------------------------------------------------------
__global__ void cvt_M(const float* __restrict__ M, __hip_bfloat16* __restrict__ out)
{
    const int g = blockIdx.x * 256 + threadIdx.x;
    if (g >= OPAD * GPR) return;
    const int o = g / GPR;
    const int k = (g - o * GPR) * 8;
    alignas(16) __hip_bfloat16 tmp[8];
    if (o < OCOLS && k + 8 <= FD) {
        const float4* p = (const float4*)(M + (size_t)o * FD + k);
        float4 x0 = p[0], x1 = p[1];
        tmp[0] = __float2bfloat16(x0.x); tmp[1] = __float2bfloat16(x0.y);
        tmp[2] = __float2bfloat16(x0.z); tmp[3] = __float2bfloat16(x0.w);
        tmp[4] = __float2bfloat16(x1.x); tmp[5] = __float2bfloat16(x1.y);
        tmp[6] = __float2bfloat16(x1.z); tmp[7] = __float2bfloat16(x1.w);
    } else {
        #pragma unroll
        for (int u = 0; u < 8; ++u) {
            float v = (o < OCOLS && k + u < FD) ? M[(size_t)o * FD + k + u] : 0.f;
            tmp[u] = __float2bfloat16(v);
        }
    }
    *(bf16x8*)(out + (size_t)o * KP + k) = *(const bf16x8*)tmp;
}

// ---------------------------------------------------------------------------
// Kernel 2: Gt[p][f] = (f<FD && alpha(p)==a(f)+j(f)) ? W[s(p),c(f)]/sqrt12 : 0
// Dense bf16 (320 x KP). Thread computes 8 consecutive f for one p.
// ---------------------------------------------------------------------------
__global__ void build_G(const float* __restrict__ W, __hip_bfloat16* __restrict__ Gt)
{
    const int g = blockIdx.x * 256 + threadIdx.x;
    if (g >= KST * GPR) return;
    const int p  = g / GPR;
    const int f0 = (g - p * GPR) * 8;
    const int s     = p / ANGD;       // 0..12 (p<300 valid)
    const int alpha = p - s * ANGD;
    const float inv = 0.28867513459481288f;
    alignas(16) __hip_bfloat16 tmp[8];
    #pragma unroll
    for (int u = 0; u < 8; ++u) {
        const int f = f0 + u;
        float v = 0.f;
        if (p < PDIM && f < FD) {
            int c, j, a;
            decode_f(f, c, j, a);
            if (alpha == a + j) v = W[s * FC + c] * inv;
        }
        tmp[u] = __float2bfloat16(v);
    }
    *(bf16x8*)(Gt + (size_t)p * KP + f0) = *(const bf16x8*)tmp;
}

// ---------------------------------------------------------------------------
// Kernel 3 (round-9 proven): X[n, s*25+a] = sk[n,s] * ang[n,a], bf16.
// ---------------------------------------------------------------------------
__global__ void build_X(const float* __restrict__ sk,
                        const float* __restrict__ ang,
                        __hip_bfloat16* __restrict__ X)
{
    const int idx = blockIdx.x * 256 + threadIdx.x;
    if (idx >= N_ROWS * (KST / 8)) return;
    const int n  = idx / (KST / 8);
    const int p0 = (idx - n * (KST / 8)) * 8;
    const float* skn  = sk  + (size_t)n * SB;
    const float* angn = ang + (size_t)n * ANGD;
    alignas(16) __hip_bfloat16 tmp[8];
    #pragma unroll
    for (int u = 0; u < 8; ++u) {
        const int p = p0 + u;
        float v = 0.f;
        if (p < PDIM) {
            const int s = p / ANGD;
            const int a = p - s * ANGD;
            v = skn[s] * angn[a];
        }
        tmp[u] = __float2bfloat16(v);
    }
    *(bf16x8*)(X + (size_t)n * KST + p0) = *(const bf16x8*)tmp;
}

// ---------------------------------------------------------------------------
// Kernel 4: V-GEMM (round-12 verified kernel, re-parameterized K=KP, NT=85).
// V[o,p] = sum_f TPb[o,f] * Gt[p,f]. Tile 128(o) x 64(p), 4 waves, BK=32.
// Epilogue: D^T frag (4 consecutive p at fixed o) -> bf16x4 normal stores
// (V is re-read by the main GEMM -> keep it cached).
// ---------------------------------------------------------------------------
__global__ __launch_bounds__(256, 4) void gemm_V(
    const __hip_bfloat16* __restrict__ A,   // TPb: (OPAD, KP)
    const __hip_bfloat16* __restrict__ B,   // Gt:  (KST, KP)
    __hip_bfloat16* __restrict__ V)         // (OPAD, KST)
{
    __shared__ __align__(1024) char lds[24576];
    char* const bufA = lds;            // 2 x 8192 B
    char* const bufB = lds + 16384;    // 2 x 4096 B

    const int tid  = threadIdx.x;
    const int wave = tid >> 6;         // 0..3
    const int lane = tid & 63;

    const int bn = blockIdx.x;         // 5 col tiles (64 p each)
    const int bm = blockIdx.y;         // 22 row tiles (128 o each)
    const size_t arow0 = (size_t)bm * 128;
    const size_t brow0 = (size_t)bn * 64;

    const int wr = wave >> 1;   // 0..1 (o half)
    const int wc = wave & 1;    // 0..1 (p half)

    const int lrow2 = lane >> 2;
    const int sslot = (((lane & 3) ^ (lrow2 & 3) ^ ((lane >> 4) & 3))) << 4;

    auto STAGE = [&](int t, int half) {
        char* const la = bufA + half * 8192;
        char* const lb = bufB + half * 4096;
        const char* ga = (const char*)A
            + (arow0 + (size_t)(wave * 16 + lrow2)) * (KP * 2)
            + (size_t)t * 64 + sslot;
        gload16(ga,                         la + wave * 1024);
        gload16(ga + (size_t)64 * (KP * 2), la + 4096 + wave * 1024);
        const char* gb = (const char*)B
            + (brow0 + (size_t)(wave * 16 + lrow2)) * (KP * 2)
            + (size_t)t * 64 + sslot;
        gload16(gb, lb + wave * 1024);
    };

    const int rl   = lane & 15;
    const int koct = lane >> 4;
    const int rslot = ((koct ^ (rl & 3) ^ ((rl >> 2) & 3))) << 4;

    STAGE(0, 0);
    STAGE(1, 1);
    asm volatile("s_waitcnt vmcnt(3)" ::: "memory");
    __builtin_amdgcn_s_barrier();

    f32x4 acc[4][2] = {};   // [m][n]; D^T: row=p, col=o

    for (int t = 0; t < NTV; ++t) {
        char* const aC = bufA + (t & 1) * 8192;
        char* const bC = bufB + (t & 1) * 4096;

        bf16x8 af[4], bfr[2];
        #pragma unroll
        for (int m = 0; m < 4; ++m) {
            const int r = wr * 64 + m * 16 + rl;
            af[m] = *(const bf16x8*)(aC + r * 64 + rslot);
        }
        #pragma unroll
        for (int n = 0; n < 2; ++n) {
            const int r = wc * 32 + n * 16 + rl;
            bfr[n] = *(const bf16x8*)(bC + r * 64 + rslot);
        }
        asm volatile("s_waitcnt lgkmcnt(0)" ::: "memory");
        __builtin_amdgcn_sched_barrier(0);
        __builtin_amdgcn_s_barrier();

        if (t + 2 < NTV) STAGE(t + 2, t & 1);

        __builtin_amdgcn_s_setprio(1);
        #pragma unroll
        for (int m = 0; m < 4; ++m)
            #pragma unroll
            for (int n = 0; n < 2; ++n)
                acc[m][n] = __builtin_amdgcn_mfma_f32_16x16x32_bf16(
                    bfr[n], af[m], acc[m][n], 0, 0, 0);
        __builtin_amdgcn_s_setprio(0);
        __builtin_amdgcn_sched_barrier(0);

        if (t < NTV - 2)       asm volatile("s_waitcnt vmcnt(3)" ::: "memory");
        else if (t == NTV - 2) asm volatile("s_waitcnt vmcnt(0)" ::: "memory");
        if (t < NTV - 1) __builtin_amdgcn_s_barrier();
    }

    // epilogue: lane has 4 consecutive p at o = arow0+wr*64+m*16+rl
    const int obase = (int)arow0 + wr * 64 + rl;
    const int pbase = (int)brow0 + wc * 32 + koct * 4;
    #pragma unroll
    for (int m = 0; m < 4; ++m) {
        const int orow = obase + m * 16;
        #pragma unroll
        for (int n = 0; n < 2; ++n) {
            const int p = pbase + n * 16;
            alignas(8) __hip_bfloat16 t4[4];
            t4[0] = __float2bfloat16(acc[m][n][0]);
            t4[1] = __float2bfloat16(acc[m][n][1]);
            t4[2] = __float2bfloat16(acc[m][n][2]);
            t4[3] = __float2bfloat16(acc[m][n][3]);
            *(uint2*)(V + (size_t)orow * KST + p) = *(const uint2*)t4;
        }
    }
}

// ---------------------------------------------------------------------------
// Kernel 5 (round-9 proven, byte-identical): main GEMM 128x128, K=320.
// ---------------------------------------------------------------------------
__global__ __launch_bounds__(512, 4) void gemm_bt(
    const __hip_bfloat16* __restrict__ A,   // X: (N_ROWS, KST)
    const __hip_bfloat16* __restrict__ B,   // V: (OPAD, KST)
    float* __restrict__ C)
{
    __shared__ __align__(1024) char lds[65536];
    char* const bufA = lds;            // 2 x 16384 B
    char* const bufB = lds + 32768;    // 2 x 16384 B
    float* const s_c = (float*)lds;    // epilogue alias: [64][132] f32

    const int tid  = threadIdx.x;
    const int wave = tid >> 6;
    const int lane = tid & 63;

    const int bn = blockIdx.x;         // 22 col tiles
    const int bm = blockIdx.y;         // 250 row tiles
    const size_t arow0 = (size_t)bm * 128;
    const size_t brow0 = (size_t)bn * 128;

    const int wr = wave >> 2;
    const int wc = wave & 3;

    const int lrow  = lane >> 3;
    const int lslot = ((lane & 7) ^ (lrow & 7)) << 4;

    auto STAGE = [&](const char* gbase, size_t growbase, int t, char* lbase) {
        const char* g0 = gbase + (growbase + (size_t)(wave * 8 + lrow)) * (KST * 2)
                               + (size_t)t * 128 + lslot;
        gload16(g0,                          lbase + wave * 1024);
        gload16(g0 + (size_t)64 * (KST * 2), lbase + 8192 + wave * 1024);
    };

    const int rl   = lane & 15;
    const int koct = lane >> 4;
    const int sK0 = ((0 * 4 + koct) ^ (lane & 7)) << 4;
    const int sK1 = ((1 * 4 + koct) ^ (lane & 7)) << 4;

    STAGE((const char*)A, arow0, 0, bufA + 0);
    STAGE((const char*)B, brow0, 0, bufB + 0);
    STAGE((const char*)A, arow0, 1, bufA + 16384);
    STAGE((const char*)B, brow0, 1, bufB + 16384);
    asm volatile("s_waitcnt vmcnt(4)" ::: "memory");
    __builtin_amdgcn_s_barrier();

    f32x4 acc[4][2] = {};

    for (int t = 0; t < NT; ++t) {
        char* const aC = bufA + (t & 1) * 16384;
        char* const bC = bufB + (t & 1) * 16384;

        bf16x8 af[4][2], bfr[2][2];
        #pragma unroll
        for (int m = 0; m < 4; ++m) {
            const int r = wr * 64 + m * 16 + rl;
            af[m][0] = *(const bf16x8*)(aC + r * 128 + sK0);
            af[m][1] = *(const bf16x8*)(aC + r * 128 + sK1);
        }
        #pragma unroll
        for (int n = 0; n < 2; ++n) {
            const int r = wc * 32 + n * 16 + rl;
            bfr[n][0] = *(const bf16x8*)(bC + r * 128 + sK0);
            bfr[n][1] = *(const bf16x8*)(bC + r * 128 + sK1);
        }
        asm volatile("s_waitcnt lgkmcnt(0)" ::: "memory");
        __builtin_amdgcn_sched_barrier(0);
        __builtin_amdgcn_s_barrier();

        if (t + 2 < NT) {
            STAGE((const char*)A, arow0, t + 2, aC);
            STAGE((const char*)B, brow0, t + 2, bC);
        }

        __builtin_amdgcn_s_setprio(1);
        #pragma unroll
        for (int ks = 0; ks < 2; ++ks)
            #pragma unroll
            for (int m = 0; m < 4; ++m)
                #pragma unroll
                for (int n = 0; n < 2; ++n)
                    acc[m][n] = __builtin_amdgcn_mfma_f32_16x16x32_bf16(
                        bfr[n][ks], af[m][ks], acc[m][n], 0, 0, 0);
        __builtin_amdgcn_s_setprio(0);
        __builtin_amdgcn_sched_barrier(0);

        if (t < NT - 2)       asm volatile("s_waitcnt vmcnt(4)" ::: "memory");
        else if (t == NT - 2) asm volatile("s_waitcnt vmcnt(0)" ::: "memory");
        if (t < NT - 1) __builtin_amdgcn_s_barrier();
    }

    #pragma unroll
    for (int h = 0; h < 2; ++h) {
        __syncthreads();
        if (wr == h) {
            #pragma unroll
            for (int m = 0; m < 4; ++m) {
                const int row_l = m * 16 + rl;
                #pragma unroll
                for (int n = 0; n < 2; ++n) {
                    const int col = wc * 32 + n * 16 + koct * 4;
                    *(f32x4*)&s_c[row_l * 132 + col] = acc[m][n];
                }
            }
        }
        __syncthreads();
        #pragma unroll
        for (int rr = 0; rr < 4; ++rr) {
            const int idx  = rr * 512 + tid;
            const int row  = idx >> 5;
            const int g4   = (idx & 31) * 4;
            if ((int)brow0 + g4 < OCOLS) {
                const f32x4 v = *(const f32x4*)&s_c[row * 132 + g4];
                __builtin_nontemporal_store(v,
                    (f32x4*)(C + (size_t)(arow0 + h * 64 + row) * OCOLS + brow0 + g4));
            }
        }
    }
}

// ---------------------------------------------------------------------------
extern "C" void kernel_launch(void* const* d_in, const int* in_sizes, int n_in,
                              void* d_out, int out_size, void* d_ws, size_t ws_size,
                              hipStream_t stream)
{
    const float* sk  = (const float*)d_in[0];   // (16,16,125,12)
    const float* ang = (const float*)d_in[1];   // (32000,25)
    const float* W   = (const float*)d_in[2];   // (12,720)
    const float* TP  = (const float*)d_in[3];   // (2704,2704)
    float* out = (float*)d_out;                 // (32000,2704)

    __hip_bfloat16* X   = (__hip_bfloat16*)d_ws;              // 20.5 MB
    __hip_bfloat16* Vb  = X   + (size_t)N_ROWS * KST;         // 1.8 MB
    __hip_bfloat16* TPb = Vb  + (size_t)OPAD * KST;           // 15.3 MB
    __hip_bfloat16* Gt  = TPb + (size_t)OPAD * KP;            // 1.74 MB

    cvt_M<<<(OPAD * GPR + 255) / 256, 256, 0, stream>>>(TP, TPb);
    build_G<<<(KST * GPR + 255) / 256, 256, 0, stream>>>(W, Gt);
    build_X<<<(N_ROWS * (KST / 8) + 255) / 256, 256, 0, stream>>>(sk, ang, X);

    dim3 gridV(KST / 64, OPAD / 128);   // (5, 22)
    gemm_V<<<gridV, 256, 0, stream>>>(TPb, Gt, Vb);

    dim3 grid(OPAD / 128, N_ROWS / 128);   // (22, 250)
    gemm_bt<<<grid, 512, 0, stream>>>(X, Vb, out);
}